// Round 2
// baseline (20113.780 us; speedup 1.0000x reference)
//
#include <hip/hip_runtime.h>

typedef unsigned short u16;
typedef __attribute__((ext_vector_type(8))) short bf16x8;
typedef __attribute__((ext_vector_type(4))) float f32x4;

// ---------------- constants ----------------
#define Bsz   128
#define TIN   512
#define TOUT  64
#define INF   64
#define OUTF  32
#define Hdim  1024
#define H3    3072

// K layouts (all multiples of 32)
#define K0    1088   // enc L0: [h(1024) | x(64)]
#define K1    2048   // enc L1: [y0(1024) | h1(1024)]
#define KD0   1120   // dec L0: [yp(32) x(64) | h(1024)]
#define KD1   2048   // dec L1: [h0in(1024) | h1(1024)]
#define KH    1024

__device__ __forceinline__ u16 f2bf(float f) {
    union { float f; unsigned u; } c; c.f = f;
    unsigned u = c.u;
    unsigned r = (u + 0x7fffu + ((u >> 16) & 1u)) >> 16;
    return (u16)r;
}

__device__ __forceinline__ f32x4 mfma16(bf16x8 a, bf16x8 b, f32x4 c) {
    return __builtin_amdgcn_mfma_f32_16x16x32_bf16(a, b, c, 0, 0, 0);
}

// ---------------- prologue kernels ----------------

// dst[row][k] = bf16( k<KA ? A[row][k] : Bs[row][k-KA] )
__global__ void __launch_bounds__(256) pack2(
        const float* __restrict__ A, int KA,
        const float* __restrict__ Bs, int KB,
        u16* __restrict__ dst) {
    int row = blockIdx.y;
    int k = blockIdx.x * 256 + threadIdx.x;
    int K = KA + KB;
    if (k >= K) return;
    float v = (k < KA) ? A[(size_t)row * KA + k] : Bs[(size_t)row * KB + (k - KA)];
    dst[(size_t)row * K + k] = f2bf(v);
}

// Bias packs: [br+bhr | bz+bhz | bin | bhn] each 1024
__global__ void __launch_bounds__(256) pack_bias(
        const float* bi0e, const float* bh0e,
        const float* bi1e, const float* bh1e,
        const float* bi0d, const float* bh0d,
        const float* bi1d, const float* bh1d,
        const float* out1b,
        float* B0, float* B1, float* BD0, float* BD1, float* HB) {
    int j = blockIdx.x * blockDim.x + threadIdx.x;
    if (j >= 1024) return;
    const float* bis[4] = { bi0e, bi1e, bi0d, bi1d };
    const float* bhs[4] = { bh0e, bh1e, bh0d, bh1d };
    float* ds[4] = { B0, B1, BD0, BD1 };
#pragma unroll
    for (int s = 0; s < 4; ++s) {
        ds[s][j]        = bis[s][j]        + bhs[s][j];
        ds[s][1024 + j] = bis[s][1024 + j] + bhs[s][1024 + j];
        ds[s][2048 + j] = bis[s][2048 + j];
        ds[s][3072 + j] = bhs[s][2048 + j];
    }
    HB[j] = out1b[j];
}

__global__ void __launch_bounds__(256) init_state(
        const float* __restrict__ enc_input,
        u16* __restrict__ X0, u16* __restrict__ X1,
        float* __restrict__ H0f, float* __restrict__ H1f) {
    int gtid = blockIdx.x * blockDim.x + threadIdx.x;
    int G = gridDim.x * blockDim.x;
    for (int i = gtid; i < Bsz * Hdim; i += G) { int b = i >> 10, j = i & 1023; X0[(size_t)b * K0 + j] = 0; }
    for (int i = gtid; i < Bsz * INF; i += G) { int b = i >> 6, f = i & 63;
        X0[(size_t)b * K0 + 1024 + f] = f2bf(enc_input[(size_t)b * (TIN * INF) + f]); }
    for (int i = gtid; i < Bsz * Hdim; i += G) { int b = i >> 10, j = i & 1023;
        X1[(size_t)(Bsz * K1) + (size_t)b * K1 + 1024 + j] = 0; }
    for (int i = gtid; i < Bsz * Hdim; i += G) { H0f[i] = 0.f; H1f[Bsz * Hdim + i] = 0.f; }
}

// ---------------- GRU tile (one WG: 16 h-cols x 64 batch) ----------------
// W: [3072][K] bf16 packed rows (r,z,n sections); X: [128][K] bf16 batch-major.
// Region [0,kbSplit) accumulates into acc2, [kbSplit,kbTotal) into acc3.
// H_FIRST=1: region0 is the h-part (hn), else region1 is.
template <int H_FIRST>
__device__ __forceinline__ void gru_tile(
    const u16* __restrict__ W, const u16* __restrict__ X,
    const float* __restrict__ Hold, const float* __restrict__ Bias,
    int K, int kbSplit, int kbTotal, int ct, int nb0,
    float* __restrict__ Hnew,
    u16* __restrict__ O1, int ld1, int off1,
    u16* __restrict__ O2, int ld2, int off2) {
    const int tid = threadIdx.x, lane = tid & 63, w = tid >> 6;
    const int l15 = lane & 15, kq = lane >> 4;
    const int j0 = ct * 16;
    const int nb = nb0 + w * 16 + l15;
    const u16* Wr = W + (size_t)(j0 + l15) * K + kq * 8;
    const u16* Wz = Wr + (size_t)1024 * K;
    const u16* Wn = Wz + (size_t)1024 * K;
    const u16* Xb = X + (size_t)nb * K + kq * 8;
    f32x4 accR = {0.f, 0.f, 0.f, 0.f};
    f32x4 accZ = {0.f, 0.f, 0.f, 0.f};
    f32x4 acc2 = {0.f, 0.f, 0.f, 0.f};
    f32x4 acc3 = {0.f, 0.f, 0.f, 0.f};
    for (int kb = 0; kb < kbSplit; ++kb) {
        const int o = kb * 32;
        bf16x8 xb = *(const bf16x8*)(Xb + o);
        accR = mfma16(*(const bf16x8*)(Wr + o), xb, accR);
        accZ = mfma16(*(const bf16x8*)(Wz + o), xb, accZ);
        acc2 = mfma16(*(const bf16x8*)(Wn + o), xb, acc2);
    }
    for (int kb = kbSplit; kb < kbTotal; ++kb) {
        const int o = kb * 32;
        bf16x8 xb = *(const bf16x8*)(Xb + o);
        accR = mfma16(*(const bf16x8*)(Wr + o), xb, accR);
        accZ = mfma16(*(const bf16x8*)(Wz + o), xb, accZ);
        acc3 = mfma16(*(const bf16x8*)(Wn + o), xb, acc3);
    }
    f32x4 accH = H_FIRST ? acc2 : acc3;  // h-part of n-gate
    f32x4 accI = H_FIRST ? acc3 : acc2;  // input-part of n-gate
#pragma unroll
    for (int q = 0; q < 4; ++q) {
        const int j = j0 + kq * 4 + q;  // D row = (lane>>4)*4 + reg
        float r = 1.f / (1.f + expf(-(accR[q] + Bias[j])));
        float z = 1.f / (1.f + expf(-(accZ[q] + Bias[1024 + j])));
        float n = tanhf(accI[q] + Bias[2048 + j] + r * (accH[q] + Bias[3072 + j]));
        float ho = Hold[(size_t)j * Bsz + nb];
        float hv = (1.f - z) * n + z * ho;
        Hnew[(size_t)j * Bsz + nb] = hv;
        u16 hb = f2bf(hv);
        O1[(size_t)nb * ld1 + off1 + j] = hb;
        if (O2) O2[(size_t)nb * ld2 + off2 + j] = hb;
    }
}

// ---------------- main round kernels (one launch per round) ----------------
struct KParams {
    const float* enc_input;
    const float* dec_input;
    const u16 *W0, *W1, *WD0, *WD1, *WH1, *WH2;
    const float *B0, *B1, *BD0, *BD1, *HB;
    u16 *X0, *X1, *XD0, *XD1, *Hhead, *Abuf;
    float *H0f, *H1f;
    float* out;
};

#define SX0  (Bsz * K0)
#define SX1  (Bsz * K1)
#define SXD0 (Bsz * KD0)
#define SXD1 (Bsz * KD1)
#define SH   (Bsz * Hdim)

// encoder round r: L0 step r (wg<128) || L1 step r-1 (wg>=128)
__global__ void __launch_bounds__(256) enc_round(KParams p, int r) {
    const int wg = blockIdx.x;
    const int pr = r & 1, pw = pr ^ 1;
    if (wg < 128) {
        if (r < 512) {
            gru_tile<1>(p.W0, p.X0 + pr * SX0, p.H0f + pr * SH, p.B0,
                        K0, 32, 34, wg >> 1, (wg & 1) * 64,
                        p.H0f + pw * SH,
                        p.X0 + pw * SX0, K0, 0,
                        p.X1 + pw * SX1, K1, 0);
            if (r + 1 < 512 && threadIdx.x < 64) {
                int b = wg, f = threadIdx.x;
                p.X0[(size_t)pw * SX0 + (size_t)b * K0 + 1024 + f] =
                    f2bf(p.enc_input[((size_t)b * TIN + (r + 1)) * INF + f]);
            }
        }
    } else {
        if (r >= 1) {
            int w2 = wg - 128;
            gru_tile<0>(p.W1, p.X1 + pr * SX1, p.H1f + pr * SH, p.B1,
                        K1, 32, 64, w2 >> 1, (w2 & 1) * 64,
                        p.H1f + pw * SH,
                        p.X1 + pw * SX1, K1, 1024,
                        (u16*)nullptr, 0, 0);
        }
    }
}

__global__ void __launch_bounds__(256) transition(KParams p) {
    int gtid = blockIdx.x * 256 + threadIdx.x;
    const int G = 256 * 256;
    float* H1a = p.H1f;              // parity 0
    float* H1b = p.H1f + SH;         // parity 1 = eh1
    for (int i = gtid; i < SH; i += G) H1a[i] = H1b[i];
    for (int i = gtid; i < Bsz * OUTF; i += G) {
        int b = i >> 5, f = i & 31;
        p.XD0[(size_t)b * KD0 + f] = f2bf(p.enc_input[((size_t)b * TIN + (TIN - 1)) * INF + f]);
    }
    for (int i = gtid; i < Bsz * INF; i += G) {
        int b = i >> 6, f = i & 63;
        p.XD0[(size_t)b * KD0 + 32 + f] = f2bf(p.dec_input[(size_t)b * (TOUT * INF) + f]);
    }
    for (int i = gtid; i < Bsz * Hdim; i += G) {
        int b = i >> 10, j = i & 1023;
        p.XD0[(size_t)b * KD0 + 96 + j] = p.X0[(size_t)b * K0 + j];  // eh0 bf16 (parity 0)
    }
    for (int i = gtid; i < Bsz * Hdim; i += G) {
        int b = i >> 10, j = i & 1023;
        p.XD1[(size_t)b * KD1 + 1024 + j] = p.X1[(size_t)SX1 + (size_t)b * K1 + 1024 + j];  // eh1 bf16
    }
}

__global__ void __launch_bounds__(256) dec_A(KParams p, int t) {
    const int wg = blockIdx.x;
    const int pt = t & 1, pn = pt ^ 1;
    gru_tile<0>(p.WD0, p.XD0 + pt * SXD0, p.H0f + pt * SH, p.BD0,
                KD0, 3, 35, wg >> 1, (wg & 1) * 64,
                p.H0f + pn * SH,
                p.XD0 + pn * SXD0, KD0, 96,
                p.XD1 + pt * SXD1, KD1, 0);
}

__global__ void __launch_bounds__(256) dec_B(KParams p, int t) {
    const int wg = blockIdx.x;
    const int pt = t & 1, pn = pt ^ 1;
    gru_tile<0>(p.WD1, p.XD1 + pt * SXD1, p.H1f + pt * SH, p.BD1,
                KD1, 32, 64, wg >> 1, (wg & 1) * 64,
                p.H1f + pn * SH,
                p.XD1 + pn * SXD1, KD1, 1024,
                p.Hhead, KH, 0);
}

// a = relu(h1 @ W1^T + b); also stage x_{t+1}
__global__ void __launch_bounds__(256) dec_C(KParams p, int t) {
    const int wg = blockIdx.x;
    const int pn = (t & 1) ^ 1;
    const int tid = threadIdx.x, lane = tid & 63, w = tid >> 6;
    const int l15 = lane & 15, kq = lane >> 4;
    const int ct = wg >> 1, nb0 = (wg & 1) * 64;
    const int j0 = ct * 16;
    const int nb = nb0 + w * 16 + l15;
    const u16* Wr = p.WH1 + (size_t)(j0 + l15) * KH + kq * 8;
    const u16* Xb = p.Hhead + (size_t)nb * KH + kq * 8;
    f32x4 acc = {0.f, 0.f, 0.f, 0.f};
    for (int kb = 0; kb < KH / 32; ++kb) {
        const int o = kb * 32;
        acc = mfma16(*(const bf16x8*)(Wr + o), *(const bf16x8*)(Xb + o), acc);
    }
#pragma unroll
    for (int q = 0; q < 4; ++q) {
        const int j = j0 + kq * 4 + q;
        float v = acc[q] + p.HB[j];
        v = v > 0.f ? v : 0.f;
        p.Abuf[(size_t)nb * KH + j] = f2bf(v);
    }
    if (t + 1 < TOUT && wg < 128 && threadIdx.x < 64) {
        int b = wg, f = threadIdx.x;
        p.XD0[(size_t)pn * SXD0 + (size_t)b * KD0 + 32 + f] =
            f2bf(p.dec_input[((size_t)b * TOUT + (t + 1)) * INF + f]);
    }
}

// out = a @ W2^T (32 x 128), 16 WGs, waves split K then LDS-reduce
__global__ void __launch_bounds__(256) dec_D(KParams p, int t) {
    __shared__ float sred[1024];
    const int wg = blockIdx.x;
    const int pn = (t & 1) ^ 1;
    const int tid = threadIdx.x, lane = tid & 63, w = tid >> 6;
    const int l15 = lane & 15, kq = lane >> 4;
    const int mt = wg & 1, nt = wg >> 1;
    const u16* Wr = p.WH2 + (size_t)(mt * 16 + l15) * KH + kq * 8;
    const u16* Xb = p.Abuf + (size_t)(nt * 16 + l15) * KH + kq * 8;
    f32x4 acc = {0.f, 0.f, 0.f, 0.f};
    for (int kb = w * 8; kb < w * 8 + 8; ++kb) {
        const int o = kb * 32;
        acc = mfma16(*(const bf16x8*)(Wr + o), *(const bf16x8*)(Xb + o), acc);
    }
#pragma unroll
    for (int q = 0; q < 4; ++q) sred[(w * 64 + lane) * 4 + q] = acc[q];
    __syncthreads();
    if (w == 0) {
#pragma unroll
        for (int q = 0; q < 4; ++q) {
            float s = sred[(0 * 64 + lane) * 4 + q] + sred[(1 * 64 + lane) * 4 + q] +
                      sred[(2 * 64 + lane) * 4 + q] + sred[(3 * 64 + lane) * 4 + q];
            int feat = mt * 16 + kq * 4 + q;
            int b = nt * 16 + l15;
            p.out[(size_t)b * (TOUT * OUTF) + t * OUTF + feat] = s;
            p.XD0[(size_t)pn * SXD0 + (size_t)b * KD0 + feat] = f2bf(s);
        }
    }
}

// ---------------- host launch ----------------
extern "C" void kernel_launch(void* const* d_in, const int* in_sizes, int n_in,
                              void* d_out, int out_size, void* d_ws, size_t ws_size,
                              hipStream_t stream) {
    const float* enc_input = (const float*)d_in[0];
    const float* dec_input = (const float*)d_in[1];
    const float* enc_Wih0 = (const float*)d_in[2];
    const float* enc_Whh0 = (const float*)d_in[3];
    const float* enc_bih0 = (const float*)d_in[4];
    const float* enc_bhh0 = (const float*)d_in[5];
    const float* enc_Wih1 = (const float*)d_in[6];
    const float* enc_Whh1 = (const float*)d_in[7];
    const float* enc_bih1 = (const float*)d_in[8];
    const float* enc_bhh1 = (const float*)d_in[9];
    const float* dec_Wih0 = (const float*)d_in[10];
    const float* dec_Whh0 = (const float*)d_in[11];
    const float* dec_bih0 = (const float*)d_in[12];
    const float* dec_bhh0 = (const float*)d_in[13];
    const float* dec_Wih1 = (const float*)d_in[14];
    const float* dec_Whh1 = (const float*)d_in[15];
    const float* dec_bih1 = (const float*)d_in[16];
    const float* dec_bhh1 = (const float*)d_in[17];
    const float* out1_W = (const float*)d_in[18];
    const float* out1_b = (const float*)d_in[19];
    const float* out2_W = (const float*)d_in[20];

    char* ws = (char*)d_ws;
    size_t off = 0;
    auto alloc = [&](size_t bytes) { size_t o = off; off = (off + bytes + 255) & ~(size_t)255; return o; };

    u16* W0 = (u16*)(ws + alloc((size_t)H3 * K0 * 2));
    u16* W1 = (u16*)(ws + alloc((size_t)H3 * K1 * 2));
    u16* WD0 = (u16*)(ws + alloc((size_t)H3 * KD0 * 2));
    u16* WD1 = (u16*)(ws + alloc((size_t)H3 * KD1 * 2));
    u16* WH1 = (u16*)(ws + alloc((size_t)Hdim * KH * 2));
    u16* WH2 = (u16*)(ws + alloc((size_t)OUTF * KH * 2));
    float* B0 = (float*)(ws + alloc(4096 * 4));
    float* B1 = (float*)(ws + alloc(4096 * 4));
    float* BD0 = (float*)(ws + alloc(4096 * 4));
    float* BD1 = (float*)(ws + alloc(4096 * 4));
    float* HB = (float*)(ws + alloc(1024 * 4));
    u16* X0 = (u16*)(ws + alloc((size_t)2 * Bsz * K0 * 2));
    u16* X1 = (u16*)(ws + alloc((size_t)2 * Bsz * K1 * 2));
    u16* XD0 = (u16*)(ws + alloc((size_t)2 * Bsz * KD0 * 2));
    u16* XD1 = (u16*)(ws + alloc((size_t)2 * Bsz * KD1 * 2));
    float* H0f = (float*)(ws + alloc((size_t)2 * Bsz * Hdim * 4));
    float* H1f = (float*)(ws + alloc((size_t)2 * Bsz * Hdim * 4));
    u16* Hhead = (u16*)(ws + alloc((size_t)Bsz * KH * 2));
    u16* Abuf = (u16*)(ws + alloc((size_t)Bsz * KH * 2));

    // --- prologue: weight/bias repack + state init ---
    pack2<<<dim3((K0 + 255) / 256, H3), 256, 0, stream>>>(enc_Whh0, 1024, enc_Wih0, 64, W0);
    pack2<<<dim3((K1 + 255) / 256, H3), 256, 0, stream>>>(enc_Wih1, 1024, enc_Whh1, 1024, W1);
    pack2<<<dim3((KD0 + 255) / 256, H3), 256, 0, stream>>>(dec_Wih0, 96, dec_Whh0, 1024, WD0);
    pack2<<<dim3((KD1 + 255) / 256, H3), 256, 0, stream>>>(dec_Wih1, 1024, dec_Whh1, 1024, WD1);
    pack2<<<dim3((KH + 255) / 256, Hdim), 256, 0, stream>>>(out1_W, 1024, nullptr, 0, WH1);
    pack2<<<dim3((KH + 255) / 256, OUTF), 256, 0, stream>>>(out2_W, 1024, nullptr, 0, WH2);
    pack_bias<<<4, 256, 0, stream>>>(enc_bih0, enc_bhh0, enc_bih1, enc_bhh1,
                                     dec_bih0, dec_bhh0, dec_bih1, dec_bhh1,
                                     out1_b, B0, B1, BD0, BD1, HB);
    init_state<<<256, 256, 0, stream>>>(enc_input, X0, X1, H0f, H1f);

    KParams kp;
    kp.enc_input = enc_input; kp.dec_input = dec_input;
    kp.W0 = W0; kp.W1 = W1; kp.WD0 = WD0; kp.WD1 = WD1; kp.WH1 = WH1; kp.WH2 = WH2;
    kp.B0 = B0; kp.B1 = B1; kp.BD0 = BD0; kp.BD1 = BD1; kp.HB = HB;
    kp.X0 = X0; kp.X1 = X1; kp.XD0 = XD0; kp.XD1 = XD1; kp.Hhead = Hhead; kp.Abuf = Abuf;
    kp.H0f = H0f; kp.H1f = H1f;
    kp.out = (float*)d_out;

    // --- encoder: 513 pipelined rounds, kernel boundary = grid barrier ---
    for (int r = 0; r < 513; ++r)
        enc_round<<<256, 256, 0, stream>>>(kp, r);

    // --- transition ---
    transition<<<256, 256, 0, stream>>>(kp);

    // --- decoder: 64 steps x 4 rounds ---
    for (int t = 0; t < TOUT; ++t) {
        dec_A<<<128, 256, 0, stream>>>(kp, t);
        dec_B<<<128, 256, 0, stream>>>(kp, t);
        dec_C<<<128, 256, 0, stream>>>(kp, t);
        dec_D<<<16, 256, 0, stream>>>(kp, t);
    }
}